// Round 2
// baseline (19176.353 us; speedup 1.0000x reference)
//
#include <hip/hip_runtime.h>
#include <hip/hip_bf16.h>

#define DH 64
#define DM 256

__device__ __forceinline__ float tanh_fast(float y) {
    float e = __expf(2.0f * y);
    return 1.0f - 2.0f / (e + 1.0f);
}

__device__ __forceinline__ float sigmoid_fast(float x) {
    return 1.0f / (1.0f + __expf(-x));
}

// ---------------------------------------------------------------------------
// Kernel A: u[t][0..63] = phi[t]·thetaQ[h], u[t][64..127] = phi[t]·thetaK[h]
// ---------------------------------------------------------------------------
__global__ __launch_bounds__(256) void proj_kernel(
    const float* __restrict__ phi,   // [T][dphi]
    const float* __restrict__ thK,   // [64][dphi]
    const float* __restrict__ thQ,   // [64][dphi]
    float* __restrict__ u,           // [T][128]
    int dphi)
{
    const int tid  = threadIdx.x;
    const int th32 = tid & 31;
    const int tt8  = tid >> 5;
    const int t0   = tt8 * 4;
    const int h0   = th32 * 4;
    const int T0   = blockIdx.x * 32;

    __shared__ float sPhiT[32][36];
    __shared__ float sThT[32][128];

    const int h   = tid >> 1;
    const int ko  = (tid & 1) * 16;
    const float* trow = (h < 64) ? (thQ + (size_t)h * dphi)
                                 : (thK + (size_t)(h - 64) * dphi);
    const int tr  = tid >> 3;
    const int k4p = (tid & 7) * 4;

    float4 pv, tv0, tv1, tv2, tv3;
    pv  = *(const float4*)&phi[(size_t)(T0 + tr) * dphi + k4p];
    tv0 = *(const float4*)&trow[ko + 0];
    tv1 = *(const float4*)&trow[ko + 4];
    tv2 = *(const float4*)&trow[ko + 8];
    tv3 = *(const float4*)&trow[ko + 12];

    float acc[4][4];
    #pragma unroll
    for (int i = 0; i < 4; ++i)
        #pragma unroll
        for (int jj = 0; jj < 4; ++jj) acc[i][jj] = 0.0f;

    const int NC = dphi / 32;
    for (int c = 0; c < NC; ++c) {
        __syncthreads();
        sPhiT[k4p + 0][tr] = pv.x;
        sPhiT[k4p + 1][tr] = pv.y;
        sPhiT[k4p + 2][tr] = pv.z;
        sPhiT[k4p + 3][tr] = pv.w;
        sThT[ko +  0][h] = tv0.x;  sThT[ko +  1][h] = tv0.y;
        sThT[ko +  2][h] = tv0.z;  sThT[ko +  3][h] = tv0.w;
        sThT[ko +  4][h] = tv1.x;  sThT[ko +  5][h] = tv1.y;
        sThT[ko +  6][h] = tv1.z;  sThT[ko +  7][h] = tv1.w;
        sThT[ko +  8][h] = tv2.x;  sThT[ko +  9][h] = tv2.y;
        sThT[ko + 10][h] = tv2.z;  sThT[ko + 11][h] = tv2.w;
        sThT[ko + 12][h] = tv3.x;  sThT[ko + 13][h] = tv3.y;
        sThT[ko + 14][h] = tv3.z;  sThT[ko + 15][h] = tv3.w;
        __syncthreads();
        if (c + 1 < NC) {
            const int kb = (c + 1) * 32;
            pv  = *(const float4*)&phi[(size_t)(T0 + tr) * dphi + kb + k4p];
            tv0 = *(const float4*)&trow[kb + ko + 0];
            tv1 = *(const float4*)&trow[kb + ko + 4];
            tv2 = *(const float4*)&trow[kb + ko + 8];
            tv3 = *(const float4*)&trow[kb + ko + 12];
        }
        #pragma unroll 8
        for (int k = 0; k < 32; ++k) {
            float4 ph = *(const float4*)&sPhiT[k][t0];
            float4 th = *(const float4*)&sThT[k][h0];
            acc[0][0] = fmaf(ph.x, th.x, acc[0][0]);
            acc[0][1] = fmaf(ph.x, th.y, acc[0][1]);
            acc[0][2] = fmaf(ph.x, th.z, acc[0][2]);
            acc[0][3] = fmaf(ph.x, th.w, acc[0][3]);
            acc[1][0] = fmaf(ph.y, th.x, acc[1][0]);
            acc[1][1] = fmaf(ph.y, th.y, acc[1][1]);
            acc[1][2] = fmaf(ph.y, th.z, acc[1][2]);
            acc[1][3] = fmaf(ph.y, th.w, acc[1][3]);
            acc[2][0] = fmaf(ph.z, th.x, acc[2][0]);
            acc[2][1] = fmaf(ph.z, th.y, acc[2][1]);
            acc[2][2] = fmaf(ph.z, th.z, acc[2][2]);
            acc[2][3] = fmaf(ph.z, th.w, acc[2][3]);
            acc[3][0] = fmaf(ph.w, th.x, acc[3][0]);
            acc[3][1] = fmaf(ph.w, th.y, acc[3][1]);
            acc[3][2] = fmaf(ph.w, th.z, acc[3][2]);
            acc[3][3] = fmaf(ph.w, th.w, acc[3][3]);
        }
    }
    #pragma unroll
    for (int i = 0; i < 4; ++i) {
        float4 o;
        o.x = acc[i][0]; o.y = acc[i][1]; o.z = acc[i][2]; o.w = acc[i][3];
        *(float4*)&u[(size_t)(T0 + t0 + i) * 128 + h0] = o;
    }
}

// ---------------------------------------------------------------------------
// Kernel B: sequential TTT scan, register-double-buffered prefetch of u(t+1),
// raw s_barrier (lgkmcnt-only drain) so prefetch loads stay in flight.
// ---------------------------------------------------------------------------

// one scan step: CU = current step's u (32 float4 = 128 f), NU gets prefetch
#define STEP(t_, CU, NU, cCur, cNext) do {                                  \
    const int tn_ = ((t_) + 1 < T) ? ((t_) + 1) : (T - 1);                  \
    const float4* un4_ = u4 + (size_t)tn_ * 32;                             \
    _Pragma("unroll")                                                       \
    for (int q_ = 0; q_ < 32; ++q_) NU[q_] = un4_[q_];                      \
    cNext = C_seq[tn_];                                                     \
    float zq0 = 0.f, zq1 = 0.f, zq2 = 0.f, zq3 = 0.f;                       \
    float zk0 = 0.f, zk1 = 0.f, zk2 = 0.f, zk3 = 0.f;                       \
    _Pragma("unroll")                                                       \
    for (int i_ = 0; i_ < 16; ++i_) {                                       \
        float4 q4 = CU[i_]; float4 k4 = CU[16 + i_];                        \
        zq0 = fmaf(q4.x, w1[4*i_+0], zq0);                                  \
        zq1 = fmaf(q4.y, w1[4*i_+1], zq1);                                  \
        zq2 = fmaf(q4.z, w1[4*i_+2], zq2);                                  \
        zq3 = fmaf(q4.w, w1[4*i_+3], zq3);                                  \
        zk0 = fmaf(k4.x, w1[4*i_+0], zk0);                                  \
        zk1 = fmaf(k4.y, w1[4*i_+1], zk1);                                  \
        zk2 = fmaf(k4.z, w1[4*i_+2], zk2);                                  \
        zk3 = fmaf(k4.w, w1[4*i_+3], zk3);                                  \
    }                                                                       \
    float zq = ((zq0 + zq1) + (zq2 + zq3)) + b1j;                           \
    float zk = ((zk0 + zk1) + (zk2 + zk3)) + b1j;                           \
    float tq = tanh_fast(0.79788456f * zq * fmaf(0.044715f, zq*zq, 1.f));   \
    float aq = 0.5f * zq * (1.f + tq);                                      \
    float tk = tanh_fast(0.79788456f * zk * fmaf(0.044715f, zk*zk, 1.f));   \
    float x2 = 0.5f * zk * (1.f + tk);                                      \
    float pq = aq * w2j;                                                    \
    float pk = x2 * w2j;                                                    \
    _Pragma("unroll")                                                       \
    for (int off_ = 32; off_ > 0; off_ >>= 1) {                             \
        pq += __shfl_xor(pq, off_);                                         \
        pk += __shfl_xor(pk, off_);                                         \
    }                                                                       \
    const int pb_ = (t_) & 1;                                               \
    if (lane == 0) { pQ[pb_][wv] = pq; pK[pb_][wv] = pk; }                  \
    asm volatile("s_waitcnt lgkmcnt(0)" ::: "memory");                      \
    __builtin_amdgcn_s_barrier();                                           \
    asm volatile("" ::: "memory");                                          \
    float zs = ((pQ[pb_][0] + pQ[pb_][1]) + (pQ[pb_][2] + pQ[pb_][3])) + b2;\
    float zp = ((pK[pb_][0] + pK[pb_][1]) + (pK[pb_][2] + pK[pb_][3])) + b2;\
    float s_   = sigmoid_fast(zs);                                          \
    float pred = sigmoid_fast(zp);                                          \
    float dZ2  = 2.f * pred * pred * (1.f - pred);                          \
    float gb   = 0.5f * zk * ((1.f - tk*tk) *                               \
                 fmaf(0.1070322243f, zk*zk, 0.79788456f))                   \
               + 0.5f * (1.f + tk);                                         \
    float dZ1 = dZ2 * w2j * gb;                                             \
    float e1  = eta * dZ1;                                                  \
    _Pragma("unroll")                                                       \
    for (int i_ = 0; i_ < 16; ++i_) {                                       \
        float4 k4 = CU[16 + i_];                                            \
        w1[4*i_+0] = fmaf(-e1, k4.x, w1[4*i_+0]);                           \
        w1[4*i_+1] = fmaf(-e1, k4.y, w1[4*i_+1]);                           \
        w1[4*i_+2] = fmaf(-e1, k4.z, w1[4*i_+2]);                           \
        w1[4*i_+3] = fmaf(-e1, k4.w, w1[4*i_+3]);                           \
    }                                                                       \
    b1j -= e1;                                                              \
    w2j  = fmaf(-eta * dZ2, x2, w2j);                                       \
    b2  -= eta * dZ2;                                                       \
    if (j == 0) out[t_] = s_;                                               \
    float d_ = s_ - cCur;                                                   \
    loss = fmaf(d_, d_, loss);                                              \
} while (0)

__global__ __launch_bounds__(256, 1) void ttt_scan(
    const float* __restrict__ u,       // [T][128]: 0..63 = u_q, 64..127 = u_k
    const float* __restrict__ C_seq,   // [T]
    const float* __restrict__ W10,     // [64][256]
    const float* __restrict__ b10,     // [256]
    const float* __restrict__ W20,     // [256]
    const float* __restrict__ b20,     // [1]
    const float* __restrict__ log_eta, // [1]
    float* __restrict__ out,           // [T+1]: scores then loss
    int T)
{
    const int j    = threadIdx.x;
    const int lane = j & 63;
    const int wv   = j >> 6;

    float w1[DH];
    #pragma unroll
    for (int i = 0; i < DH; ++i) w1[i] = W10[i * DM + j];
    float b1j = b10[j];
    float w2j = W20[j];
    float b2  = b20[0];
    const float eta = __expf(log_eta[0]);
    float loss = 0.0f;

    __shared__ float pQ[2][4];
    __shared__ float pK[2][4];

    const float4* u4 = (const float4*)u;
    float4 ua[32], ub[32];
    #pragma unroll
    for (int q = 0; q < 32; ++q) ua[q] = u4[q];
    float cA = C_seq[0], cB;

    for (int t = 0; t < T; t += 2) {
        STEP(t,     ua, ub, cA, cB);
        STEP(t + 1, ub, ua, cB, cA);
    }
    if (j == 0) out[T] = loss;
}

// ---------------------------------------------------------------------------
extern "C" void kernel_launch(void* const* d_in, const int* in_sizes, int n_in,
                              void* d_out, int out_size, void* d_ws, size_t ws_size,
                              hipStream_t stream) {
    const float* phi     = (const float*)d_in[0];
    const float* C_seq   = (const float*)d_in[1];
    const float* thK     = (const float*)d_in[2];
    const float* thQ     = (const float*)d_in[3];
    const float* W10     = (const float*)d_in[4];
    const float* b10     = (const float*)d_in[5];
    const float* W20     = (const float*)d_in[6];
    const float* b20     = (const float*)d_in[7];
    const float* log_eta = (const float*)d_in[8];

    const int T    = in_sizes[1];          // 8192
    const int dphi = in_sizes[0] / T;      // 4096

    float* u = (float*)d_ws;               // [T][128] = 4 MB

    proj_kernel<<<T / 32, 256, 0, stream>>>(phi, thK, thQ, u, dphi);
    ttt_scan<<<1, 256, 0, stream>>>(u, C_seq, W10, b10, W20, b20, log_eta,
                                    (float*)d_out, T);
}

// Round 3
// 9849.969 us; speedup vs baseline: 1.9468x; 1.9468x over previous
//
#include <hip/hip_runtime.h>
#include <hip/hip_bf16.h>

#define DH 64
#define DM 256

__device__ __forceinline__ float tanh_fast(float y) {
    float e = __expf(2.0f * y);
    return 1.0f - 2.0f / (e + 1.0f);
}

__device__ __forceinline__ float sigmoid_fast(float x) {
    return 1.0f / (1.0f + __expf(-x));
}

// ---------------------------------------------------------------------------
// Kernel A: u[t][0..63] = phi[t]·thetaQ[h], u[t][64..127] = phi[t]·thetaK[h]
// ---------------------------------------------------------------------------
__global__ __launch_bounds__(256) void proj_kernel(
    const float* __restrict__ phi,   // [T][dphi]
    const float* __restrict__ thK,   // [64][dphi]
    const float* __restrict__ thQ,   // [64][dphi]
    float* __restrict__ u,           // [T][128]
    int dphi)
{
    const int tid  = threadIdx.x;
    const int th32 = tid & 31;
    const int tt8  = tid >> 5;
    const int t0   = tt8 * 4;
    const int h0   = th32 * 4;
    const int T0   = blockIdx.x * 32;

    __shared__ float sPhiT[32][36];
    __shared__ float sThT[32][128];

    const int h   = tid >> 1;
    const int ko  = (tid & 1) * 16;
    const float* trow = (h < 64) ? (thQ + (size_t)h * dphi)
                                 : (thK + (size_t)(h - 64) * dphi);
    const int tr  = tid >> 3;
    const int k4p = (tid & 7) * 4;

    float4 pv, tv0, tv1, tv2, tv3;
    pv  = *(const float4*)&phi[(size_t)(T0 + tr) * dphi + k4p];
    tv0 = *(const float4*)&trow[ko + 0];
    tv1 = *(const float4*)&trow[ko + 4];
    tv2 = *(const float4*)&trow[ko + 8];
    tv3 = *(const float4*)&trow[ko + 12];

    float acc[4][4];
    #pragma unroll
    for (int i = 0; i < 4; ++i)
        #pragma unroll
        for (int jj = 0; jj < 4; ++jj) acc[i][jj] = 0.0f;

    const int NC = dphi / 32;
    for (int c = 0; c < NC; ++c) {
        __syncthreads();
        sPhiT[k4p + 0][tr] = pv.x;
        sPhiT[k4p + 1][tr] = pv.y;
        sPhiT[k4p + 2][tr] = pv.z;
        sPhiT[k4p + 3][tr] = pv.w;
        sThT[ko +  0][h] = tv0.x;  sThT[ko +  1][h] = tv0.y;
        sThT[ko +  2][h] = tv0.z;  sThT[ko +  3][h] = tv0.w;
        sThT[ko +  4][h] = tv1.x;  sThT[ko +  5][h] = tv1.y;
        sThT[ko +  6][h] = tv1.z;  sThT[ko +  7][h] = tv1.w;
        sThT[ko +  8][h] = tv2.x;  sThT[ko +  9][h] = tv2.y;
        sThT[ko + 10][h] = tv2.z;  sThT[ko + 11][h] = tv2.w;
        sThT[ko + 12][h] = tv3.x;  sThT[ko + 13][h] = tv3.y;
        sThT[ko + 14][h] = tv3.z;  sThT[ko + 15][h] = tv3.w;
        __syncthreads();
        if (c + 1 < NC) {
            const int kb = (c + 1) * 32;
            pv  = *(const float4*)&phi[(size_t)(T0 + tr) * dphi + kb + k4p];
            tv0 = *(const float4*)&trow[kb + ko + 0];
            tv1 = *(const float4*)&trow[kb + ko + 4];
            tv2 = *(const float4*)&trow[kb + ko + 8];
            tv3 = *(const float4*)&trow[kb + ko + 12];
        }
        #pragma unroll 8
        for (int k = 0; k < 32; ++k) {
            float4 ph = *(const float4*)&sPhiT[k][t0];
            float4 th = *(const float4*)&sThT[k][h0];
            acc[0][0] = fmaf(ph.x, th.x, acc[0][0]);
            acc[0][1] = fmaf(ph.x, th.y, acc[0][1]);
            acc[0][2] = fmaf(ph.x, th.z, acc[0][2]);
            acc[0][3] = fmaf(ph.x, th.w, acc[0][3]);
            acc[1][0] = fmaf(ph.y, th.x, acc[1][0]);
            acc[1][1] = fmaf(ph.y, th.y, acc[1][1]);
            acc[1][2] = fmaf(ph.y, th.z, acc[1][2]);
            acc[1][3] = fmaf(ph.y, th.w, acc[1][3]);
            acc[2][0] = fmaf(ph.z, th.x, acc[2][0]);
            acc[2][1] = fmaf(ph.z, th.y, acc[2][1]);
            acc[2][2] = fmaf(ph.z, th.z, acc[2][2]);
            acc[2][3] = fmaf(ph.z, th.w, acc[2][3]);
            acc[3][0] = fmaf(ph.w, th.x, acc[3][0]);
            acc[3][1] = fmaf(ph.w, th.y, acc[3][1]);
            acc[3][2] = fmaf(ph.w, th.z, acc[3][2]);
            acc[3][3] = fmaf(ph.w, th.w, acc[3][3]);
        }
    }
    #pragma unroll
    for (int i = 0; i < 4; ++i) {
        float4 o;
        o.x = acc[i][0]; o.y = acc[i][1]; o.z = acc[i][2]; o.w = acc[i][3];
        *(float4*)&u[(size_t)(T0 + t0 + i) * 128 + h0] = o;
    }
}

// ---------------------------------------------------------------------------
// Kernel B: sequential TTT scan.
//  - u staged in bulk 64-step blocks into LDS (2x32KB double buffer):
//    loads issued at r==0 for block B+1, ds_write at r==32 (latency hidden).
//  - per-step u reads are uniform-address ds_read_b128 (broadcast).
//  - one raw s_barrier per step, lgkmcnt-only drain (global stores / staging
//    loads stay in flight).
// ---------------------------------------------------------------------------
__global__ __launch_bounds__(256, 1) void ttt_scan(
    const float* __restrict__ u,       // [T][128]: 0..63 = u_q, 64..127 = u_k
    const float* __restrict__ C_seq,   // [T]
    const float* __restrict__ W10,     // [64][256]
    const float* __restrict__ b10,     // [256]
    const float* __restrict__ W20,     // [256]
    const float* __restrict__ b20,     // [1]
    const float* __restrict__ log_eta, // [1]
    float* __restrict__ out,           // [T+1]: scores then loss
    int T)
{
    const int j    = threadIdx.x;
    const int lane = j & 63;
    const int wv   = j >> 6;

    float w1[DH];
    #pragma unroll
    for (int i = 0; i < DH; ++i) w1[i] = W10[i * DM + j];
    float b1j = b10[j];
    float w2j = W20[j];
    float b2  = b20[0];
    const float eta = __expf(log_eta[0]);
    float loss = 0.0f;

    __shared__ float ubuf[2][64 * 128];   // 2 x 32 KB
    __shared__ float cbuf[2][64];
    __shared__ float pQ[2][4];
    __shared__ float pK[2][4];

    const int NB = T >> 6;                // 64-step blocks

    // prologue: stage block 0 directly
    #pragma unroll
    for (int q = 0; q < 8; ++q) {
        float4 v = *(const float4*)&u[q * 1024 + j * 4];
        *(float4*)&ubuf[0][q * 1024 + j * 4] = v;
    }
    if (j < 16) {
        float4 c4 = *(const float4*)&C_seq[j * 4];
        *(float4*)&cbuf[0][j * 4] = c4;
    }
    __syncthreads();

    float4 st[8];
    float4 stc = make_float4(0.f, 0.f, 0.f, 0.f);

    for (int t = 0; t < T; ++t) {
        const int r    = t & 63;
        const int B    = t >> 6;
        const int bsel = B & 1;

        if (r == 0 && B + 1 < NB) {
            // issue next block's loads (consumed 32 steps later)
            const float* src = u + (size_t)(B + 1) * 8192;
            #pragma unroll
            for (int q = 0; q < 8; ++q)
                st[q] = *(const float4*)&src[q * 1024 + j * 4];
            if (j < 16)
                stc = *(const float4*)&C_seq[(B + 1) * 64 + j * 4];
        }
        if (r == 32 && B + 1 < NB) {
            #pragma unroll
            for (int q = 0; q < 8; ++q)
                *(float4*)&ubuf[bsel ^ 1][q * 1024 + j * 4] = st[q];
            if (j < 16)
                *(float4*)&cbuf[bsel ^ 1][j * 4] = stc;
        }

        const float* urow = &ubuf[bsel][r * 128];

        // dual matvec vs register-resident W1 column, 8 split accumulators
        float zq0 = 0.f, zq1 = 0.f, zq2 = 0.f, zq3 = 0.f;
        float zk0 = 0.f, zk1 = 0.f, zk2 = 0.f, zk3 = 0.f;
        float4 kf[16];
        #pragma unroll
        for (int i = 0; i < 16; ++i) {
            float4 q4 = *(const float4*)&urow[i * 4];        // broadcast ds_read
            float4 k4 = *(const float4*)&urow[64 + i * 4];
            kf[i] = k4;
            zq0 = fmaf(q4.x, w1[4 * i + 0], zq0);
            zq1 = fmaf(q4.y, w1[4 * i + 1], zq1);
            zq2 = fmaf(q4.z, w1[4 * i + 2], zq2);
            zq3 = fmaf(q4.w, w1[4 * i + 3], zq3);
            zk0 = fmaf(k4.x, w1[4 * i + 0], zk0);
            zk1 = fmaf(k4.y, w1[4 * i + 1], zk1);
            zk2 = fmaf(k4.z, w1[4 * i + 2], zk2);
            zk3 = fmaf(k4.w, w1[4 * i + 3], zk3);
        }
        float zq = ((zq0 + zq1) + (zq2 + zq3)) + b1j;
        float zk = ((zk0 + zk1) + (zk2 + zk3)) + b1j;

        float tq = tanh_fast(0.79788456f * zq * fmaf(0.044715f, zq * zq, 1.f));
        float aq = 0.5f * zq * (1.f + tq);
        float tk = tanh_fast(0.79788456f * zk * fmaf(0.044715f, zk * zk, 1.f));
        float x2 = 0.5f * zk * (1.f + tk);

        float pq = aq * w2j;
        float pk = x2 * w2j;
        #pragma unroll
        for (int off = 32; off > 0; off >>= 1) {
            pq += __shfl_xor(pq, off);
            pk += __shfl_xor(pk, off);
        }
        const int pb = t & 1;
        if (lane == 0) { pQ[pb][wv] = pq; pK[pb][wv] = pk; }
        asm volatile("s_waitcnt lgkmcnt(0)" ::: "memory");
        __builtin_amdgcn_s_barrier();
        asm volatile("" ::: "memory");
        float zs = ((pQ[pb][0] + pQ[pb][1]) + (pQ[pb][2] + pQ[pb][3])) + b2;
        float zp = ((pK[pb][0] + pK[pb][1]) + (pK[pb][2] + pK[pb][3])) + b2;

        float s_   = sigmoid_fast(zs);
        float pred = sigmoid_fast(zp);
        float dZ2  = 2.f * pred * pred * (1.f - pred);
        float gb   = 0.5f * zk * ((1.f - tk * tk) *
                     fmaf(0.1070322243f, zk * zk, 0.79788456f))
                   + 0.5f * (1.f + tk);
        float dZ1 = dZ2 * w2j * gb;
        float e1  = eta * dZ1;

        #pragma unroll
        for (int i = 0; i < 16; ++i) {
            float4 k4 = kf[i];
            w1[4 * i + 0] = fmaf(-e1, k4.x, w1[4 * i + 0]);
            w1[4 * i + 1] = fmaf(-e1, k4.y, w1[4 * i + 1]);
            w1[4 * i + 2] = fmaf(-e1, k4.z, w1[4 * i + 2]);
            w1[4 * i + 3] = fmaf(-e1, k4.w, w1[4 * i + 3]);
        }
        b1j -= e1;
        w2j  = fmaf(-eta * dZ2, x2, w2j);
        b2  -= eta * dZ2;

        float c = cbuf[bsel][r];
        if (j == 0) out[t] = s_;
        float d_ = s_ - c;
        loss = fmaf(d_, d_, loss);
    }
    if (j == 0) out[T] = loss;
}

// ---------------------------------------------------------------------------
extern "C" void kernel_launch(void* const* d_in, const int* in_sizes, int n_in,
                              void* d_out, int out_size, void* d_ws, size_t ws_size,
                              hipStream_t stream) {
    const float* phi     = (const float*)d_in[0];
    const float* C_seq   = (const float*)d_in[1];
    const float* thK     = (const float*)d_in[2];
    const float* thQ     = (const float*)d_in[3];
    const float* W10     = (const float*)d_in[4];
    const float* b10     = (const float*)d_in[5];
    const float* W20     = (const float*)d_in[6];
    const float* b20     = (const float*)d_in[7];
    const float* log_eta = (const float*)d_in[8];

    const int T    = in_sizes[1];          // 8192
    const int dphi = in_sizes[0] / T;      // 4096

    float* u = (float*)d_ws;               // [T][128] = 4 MB

    proj_kernel<<<T / 32, 256, 0, stream>>>(phi, thK, thQ, u, dphi);
    ttt_scan<<<1, 256, 0, stream>>>(u, C_seq, W10, b10, W20, b20, log_eta,
                                    (float*)d_out, T);
}

// Round 5
// 8722.542 us; speedup vs baseline: 2.1985x; 1.1293x over previous
//
#include <hip/hip_runtime.h>
#include <hip/hip_bf16.h>

#define DH 64
#define DM 256

__device__ __forceinline__ float tanh_fast(float y) {
    float e = __expf(2.0f * y);
    return 1.0f - 2.0f / (e + 1.0f);
}

__device__ __forceinline__ float sigmoid_fast(float x) {
    return 1.0f / (1.0f + __expf(-x));
}

// DPP butterfly sum over 64 lanes; total lands in lane 63 (other lanes partial).
template <int CTRL, int RMASK>
__device__ __forceinline__ float dpp_term(float x) {
    int p = __builtin_amdgcn_update_dpp(0, __float_as_int(x), CTRL, RMASK, 0xf, false);
    return __int_as_float(p);
}
__device__ __forceinline__ float wave_sum63(float x) {
    x += dpp_term<0xB1,  0xf>(x);   // quad_perm [1,0,3,2]  (xor 1)
    x += dpp_term<0x4E,  0xf>(x);   // quad_perm [2,3,0,1]  (xor 2)
    x += dpp_term<0x141, 0xf>(x);   // row_half_mirror      (xor 4)
    x += dpp_term<0x140, 0xf>(x);   // row_mirror           (xor 8)
    x += dpp_term<0x142, 0xa>(x);   // row_bcast15 -> rows 1,3
    x += dpp_term<0x143, 0xc>(x);   // row_bcast31 -> rows 2,3
    return x;                       // lane 63 = full sum
}

// ---------------------------------------------------------------------------
// Kernel A: u[t][0..63] = phi[t]·thetaQ[h], u[t][64..127] = phi[t]·thetaK[h]
// ---------------------------------------------------------------------------
__global__ __launch_bounds__(256) void proj_kernel(
    const float* __restrict__ phi,   // [T][dphi]
    const float* __restrict__ thK,   // [64][dphi]
    const float* __restrict__ thQ,   // [64][dphi]
    float* __restrict__ u,           // [T][128]
    int dphi)
{
    const int tid  = threadIdx.x;
    const int th32 = tid & 31;
    const int tt8  = tid >> 5;
    const int t0   = tt8 * 4;
    const int h0   = th32 * 4;
    const int T0   = blockIdx.x * 32;

    __shared__ float sPhiT[32][36];
    __shared__ float sThT[32][128];

    const int h   = tid >> 1;
    const int ko  = (tid & 1) * 16;
    const float* trow = (h < 64) ? (thQ + (size_t)h * dphi)
                                 : (thK + (size_t)(h - 64) * dphi);
    const int tr  = tid >> 3;
    const int k4p = (tid & 7) * 4;

    float4 pv, tv0, tv1, tv2, tv3;
    pv  = *(const float4*)&phi[(size_t)(T0 + tr) * dphi + k4p];
    tv0 = *(const float4*)&trow[ko + 0];
    tv1 = *(const float4*)&trow[ko + 4];
    tv2 = *(const float4*)&trow[ko + 8];
    tv3 = *(const float4*)&trow[ko + 12];

    float acc[4][4];
    #pragma unroll
    for (int i = 0; i < 4; ++i)
        #pragma unroll
        for (int jj = 0; jj < 4; ++jj) acc[i][jj] = 0.0f;

    const int NC = dphi / 32;
    for (int c = 0; c < NC; ++c) {
        __syncthreads();
        sPhiT[k4p + 0][tr] = pv.x;
        sPhiT[k4p + 1][tr] = pv.y;
        sPhiT[k4p + 2][tr] = pv.z;
        sPhiT[k4p + 3][tr] = pv.w;
        sThT[ko +  0][h] = tv0.x;  sThT[ko +  1][h] = tv0.y;
        sThT[ko +  2][h] = tv0.z;  sThT[ko +  3][h] = tv0.w;
        sThT[ko +  4][h] = tv1.x;  sThT[ko +  5][h] = tv1.y;
        sThT[ko +  6][h] = tv1.z;  sThT[ko +  7][h] = tv1.w;
        sThT[ko +  8][h] = tv2.x;  sThT[ko +  9][h] = tv2.y;
        sThT[ko + 10][h] = tv2.z;  sThT[ko + 11][h] = tv2.w;
        sThT[ko + 12][h] = tv3.x;  sThT[ko + 13][h] = tv3.y;
        sThT[ko + 14][h] = tv3.z;  sThT[ko + 15][h] = tv3.w;
        __syncthreads();
        if (c + 1 < NC) {
            const int kb = (c + 1) * 32;
            pv  = *(const float4*)&phi[(size_t)(T0 + tr) * dphi + kb + k4p];
            tv0 = *(const float4*)&trow[kb + ko + 0];
            tv1 = *(const float4*)&trow[kb + ko + 4];
            tv2 = *(const float4*)&trow[kb + ko + 8];
            tv3 = *(const float4*)&trow[kb + ko + 12];
        }
        #pragma unroll 8
        for (int k = 0; k < 32; ++k) {
            float4 ph = *(const float4*)&sPhiT[k][t0];
            float4 th = *(const float4*)&sThT[k][h0];
            acc[0][0] = fmaf(ph.x, th.x, acc[0][0]);
            acc[0][1] = fmaf(ph.x, th.y, acc[0][1]);
            acc[0][2] = fmaf(ph.x, th.z, acc[0][2]);
            acc[0][3] = fmaf(ph.x, th.w, acc[0][3]);
            acc[1][0] = fmaf(ph.y, th.x, acc[1][0]);
            acc[1][1] = fmaf(ph.y, th.y, acc[1][1]);
            acc[1][2] = fmaf(ph.y, th.z, acc[1][2]);
            acc[1][3] = fmaf(ph.y, th.w, acc[1][3]);
            acc[2][0] = fmaf(ph.z, th.x, acc[2][0]);
            acc[2][1] = fmaf(ph.z, th.y, acc[2][1]);
            acc[2][2] = fmaf(ph.z, th.z, acc[2][2]);
            acc[2][3] = fmaf(ph.z, th.w, acc[2][3]);
            acc[3][0] = fmaf(ph.w, th.x, acc[3][0]);
            acc[3][1] = fmaf(ph.w, th.y, acc[3][1]);
            acc[3][2] = fmaf(ph.w, th.z, acc[3][2]);
            acc[3][3] = fmaf(ph.w, th.w, acc[3][3]);
        }
    }
    #pragma unroll
    for (int i = 0; i < 4; ++i) {
        float4 o;
        o.x = acc[i][0]; o.y = acc[i][1]; o.z = acc[i][2]; o.w = acc[i][3];
        *(float4*)&u[(size_t)(T0 + t0 + i) * 128 + h0] = o;
    }
}

// ---------------------------------------------------------------------------
// Kernel A2: dd[t*2]   = u_k(t)·u_q(t+1)
//            dd[t*2+1] = u_k(t)·u_k(t+1)   (dd[T-1] = 0,0)
// ---------------------------------------------------------------------------
__global__ __launch_bounds__(256) void dots_kernel(
    const float* __restrict__ u, float* __restrict__ dd, int T)
{
    const int t    = (blockIdx.x * 256 + threadIdx.x) >> 6;
    const int lane = threadIdx.x & 63;
    if (t >= T) return;
    float a = 0.f, q = 0.f, k = 0.f;
    if (t < T - 1) {
        a = u[(size_t)t * 128 + 64 + lane];
        q = u[(size_t)(t + 1) * 128 + lane];
        k = u[(size_t)(t + 1) * 128 + 64 + lane];
    }
    float p1 = a * q, p2 = a * k;
    #pragma unroll
    for (int off = 32; off > 0; off >>= 1) {
        p1 += __shfl_xor(p1, off);
        p2 += __shfl_xor(p2, off);
    }
    if (lane == 0) { dd[t * 2] = p1; dd[t * 2 + 1] = p2; }
}

// ---------------------------------------------------------------------------
// Kernel B: sequential TTT scan, 1-step-deferred matvec.
//   z(t+1)[j] = u(t+1)·W1(t)_j + b1(t)[j] - e1(t)[j]*(u_k(t)·u(t+1) + 1)
// so the 128-FMA dual matvec M(t+1) is issued right after the barrier and
// overlaps the partial-read + sigmoid/dZ1 chain of step t. Dots precomputed.
// DPP butterfly (VALU) replaces ds_bpermute shuffles for the 64-lane reduce.
// ---------------------------------------------------------------------------

#define STEP(t_, UKC, UKN) do {                                             \
    const int r_  = (t_) & 63;                                              \
    const int B_  = (t_) >> 6;                                              \
    const int bs_ = B_ & 1;                                                 \
    /* current-step activations (zq, zk precomputed) */                     \
    float tk_ = tanh_fast(0.79788456f * zk * fmaf(0.044715f, zk * zk, 1.f));\
    float x2_ = 0.5f * zk * (1.f + tk_);                                    \
    float tq_ = tanh_fast(0.79788456f * zq * fmaf(0.044715f, zq * zq, 1.f));\
    float aq_ = 0.5f * zq * (1.f + tq_);                                    \
    float pq_ = wave_sum63(aq_ * w2j);                                      \
    float pk_ = wave_sum63(x2_ * w2j);                                      \
    const int pb_ = (t_) & 1;                                               \
    if (lane == 63) { pQ[pb_][wv] = pq_; pK[pb_][wv] = pk_; }               \
    asm volatile("s_waitcnt lgkmcnt(0)" ::: "memory");                      \
    __builtin_amdgcn_s_barrier();                                           \
    asm volatile("" ::: "memory");                                          \
    float4 pq4_ = *(const float4*)&pQ[pb_][0];                              \
    float4 pk4_ = *(const float4*)&pK[pb_][0];                              \
    float2 dd2_ = *(const float2*)&dbuf[bs_][r_ * 2];                       \
    float  c_   = cbuf[bs_][r_];                                            \
    if (r_ == 0 && B_ + 1 < NB) {                                           \
        const float* src_ = u + (size_t)(B_ + 1) * 8192;                    \
        _Pragma("unroll")                                                   \
        for (int q_ = 0; q_ < 8; ++q_)                                      \
            st[q_] = *(const float4*)&src_[q_ * 1024 + j * 4];              \
        if (j < 16) stc = *(const float4*)&C_seq[(B_ + 1) * 64 + j * 4];    \
        if (j >= 32 && j < 64)                                              \
            std = *(const float4*)&dd_g[(B_ + 1) * 128 + (j - 32) * 4];     \
    }                                                                       \
    if (r_ == 32 && B_ + 1 < NB) {                                          \
        _Pragma("unroll")                                                   \
        for (int q_ = 0; q_ < 8; ++q_)                                      \
            *(float4*)&ubuf[bs_ ^ 1][q_ * 1024 + j * 4] = st[q_];           \
        if (j < 16) *(float4*)&cbuf[bs_ ^ 1][j * 4] = stc;                  \
        if (j >= 32 && j < 64)                                              \
            *(float4*)&dbuf[bs_ ^ 1][(j - 32) * 4] = std;                   \
    }                                                                       \
    /* next-step dual matvec vs W1(t) — fills the post-barrier stall */     \
    const float* urow_ = (r_ < 63) ? &ubuf[bs_][(r_ + 1) * 128]             \
                                   : &ubuf[bs_ ^ 1][0];                     \
    float mq0 = 0.f, mq1 = 0.f, mq2 = 0.f, mq3 = 0.f;                       \
    float mk0 = 0.f, mk1 = 0.f, mk2 = 0.f, mk3 = 0.f;                       \
    _Pragma("unroll")                                                       \
    for (int i_ = 0; i_ < 16; ++i_) {                                       \
        float4 q4_ = *(const float4*)&urow_[i_ * 4];                        \
        float4 k4_ = *(const float4*)&urow_[64 + i_ * 4];                   \
        UKN[i_] = k4_;                                                      \
        mq0 = fmaf(q4_.x, w1[4 * i_ + 0], mq0);                             \
        mq1 = fmaf(q4_.y, w1[4 * i_ + 1], mq1);                             \
        mq2 = fmaf(q4_.z, w1[4 * i_ + 2], mq2);                             \
        mq3 = fmaf(q4_.w, w1[4 * i_ + 3], mq3);                             \
        mk0 = fmaf(k4_.x, w1[4 * i_ + 0], mk0);                             \
        mk1 = fmaf(k4_.y, w1[4 * i_ + 1], mk1);                             \
        mk2 = fmaf(k4_.z, w1[4 * i_ + 2], mk2);                             \
        mk3 = fmaf(k4_.w, w1[4 * i_ + 3], mk3);                             \
    }                                                                       \
    float mq_ = (mq0 + mq1) + (mq2 + mq3);                                  \
    float mk_ = (mk0 + mk1) + (mk2 + mk3);                                  \
    /* finish current step */                                               \
    float zs_ = ((pq4_.x + pq4_.y) + (pq4_.z + pq4_.w)) + b2;               \
    float zp_ = ((pk4_.x + pk4_.y) + (pk4_.z + pk4_.w)) + b2;               \
    float s_    = sigmoid_fast(zs_);                                        \
    float pred_ = sigmoid_fast(zp_);                                        \
    float dZ2_  = 2.f * pred_ * pred_ * (1.f - pred_);                      \
    float gb_   = 0.5f * zk * ((1.f - tk_ * tk_) *                          \
                  fmaf(0.1070322243f, zk * zk, 0.79788456f))                \
                + 0.5f * (1.f + tk_);                                       \
    float dZ1_ = dZ2_ * w2j * gb_;                                          \
    float e1_  = eta * dZ1_;                                                \
    /* fixup -> next-step preactivations */                                 \
    zq = fmaf(-e1_, dd2_.x + 1.f, mq_ + b1j);                               \
    zk = fmaf(-e1_, dd2_.y + 1.f, mk_ + b1j);                               \
    /* state update */                                                      \
    _Pragma("unroll")                                                       \
    for (int i_ = 0; i_ < 16; ++i_) {                                       \
        float4 k4_ = UKC[i_];                                               \
        w1[4 * i_ + 0] = fmaf(-e1_, k4_.x, w1[4 * i_ + 0]);                 \
        w1[4 * i_ + 1] = fmaf(-e1_, k4_.y, w1[4 * i_ + 1]);                 \
        w1[4 * i_ + 2] = fmaf(-e1_, k4_.z, w1[4 * i_ + 2]);                 \
        w1[4 * i_ + 3] = fmaf(-e1_, k4_.w, w1[4 * i_ + 3]);                 \
    }                                                                       \
    b1j -= e1_;                                                             \
    w2j  = fmaf(-eta * dZ2_, x2_, w2j);                                     \
    b2  -= eta * dZ2_;                                                      \
    if (j == 0) out[t_] = s_;                                               \
    float df_ = s_ - c_;                                                    \
    loss = fmaf(df_, df_, loss);                                            \
} while (0)

__global__ __launch_bounds__(256, 1) void ttt_scan(
    const float* __restrict__ u,       // [T][128]
    const float* __restrict__ dd_g,    // [T][2] precomputed dots
    const float* __restrict__ C_seq,   // [T]
    const float* __restrict__ W10,     // [64][256]
    const float* __restrict__ b10,     // [256]
    const float* __restrict__ W20,     // [256]
    const float* __restrict__ b20,     // [1]
    const float* __restrict__ log_eta, // [1]
    float* __restrict__ out,           // [T+1]
    int T)
{
    const int j    = threadIdx.x;
    const int lane = j & 63;
    const int wv   = j >> 6;

    float w1[DH];
    #pragma unroll
    for (int i = 0; i < DH; ++i) w1[i] = W10[i * DM + j];
    float b1j = b10[j];
    float w2j = W20[j];
    float b2  = b20[0];
    const float eta = __expf(log_eta[0]);
    float loss = 0.0f;

    __shared__ __align__(16) float ubuf[2][64 * 128];   // 2 x 32 KB
    __shared__ __align__(16) float cbuf[2][64];
    __shared__ __align__(16) float dbuf[2][128];
    __shared__ __align__(16) float pQ[2][4];
    __shared__ __align__(16) float pK[2][4];

    const int NB = T >> 6;

    // prologue: stage block 0
    #pragma unroll
    for (int q = 0; q < 8; ++q) {
        float4 v = *(const float4*)&u[q * 1024 + j * 4];
        *(float4*)&ubuf[0][q * 1024 + j * 4] = v;
    }
    if (j < 16) {
        float4 c4 = *(const float4*)&C_seq[j * 4];
        *(float4*)&cbuf[0][j * 4] = c4;
    }
    if (j >= 32 && j < 64) {
        float4 d4 = *(const float4*)&dd_g[(j - 32) * 4];
        *(float4*)&dbuf[0][(j - 32) * 4] = d4;
    }
    __syncthreads();

    float4 ua[16], ub[16];
    float4 st[8];
    float4 stc = make_float4(0.f, 0.f, 0.f, 0.f);
    float4 std = make_float4(0.f, 0.f, 0.f, 0.f);

    // peel: compute z(0) directly from W1(0)
    float zq, zk;
    {
        const float* urow = &ubuf[0][0];
        float a0 = 0.f, a1 = 0.f, a2 = 0.f, a3 = 0.f;
        float c0 = 0.f, c1 = 0.f, c2 = 0.f, c3 = 0.f;
        #pragma unroll
        for (int i = 0; i < 16; ++i) {
            float4 q4 = *(const float4*)&urow[i * 4];
            float4 k4 = *(const float4*)&urow[64 + i * 4];
            ua[i] = k4;
            a0 = fmaf(q4.x, w1[4 * i + 0], a0);
            a1 = fmaf(q4.y, w1[4 * i + 1], a1);
            a2 = fmaf(q4.z, w1[4 * i + 2], a2);
            a3 = fmaf(q4.w, w1[4 * i + 3], a3);
            c0 = fmaf(k4.x, w1[4 * i + 0], c0);
            c1 = fmaf(k4.y, w1[4 * i + 1], c1);
            c2 = fmaf(k4.z, w1[4 * i + 2], c2);
            c3 = fmaf(k4.w, w1[4 * i + 3], c3);
        }
        zq = ((a0 + a1) + (a2 + a3)) + b1j;
        zk = ((c0 + c1) + (c2 + c3)) + b1j;
    }

    for (int t = 0; t < T; t += 2) {
        STEP(t,     ua, ub);
        STEP(t + 1, ub, ua);
    }
    if (j == 0) out[T] = loss;
}

// ---------------------------------------------------------------------------
extern "C" void kernel_launch(void* const* d_in, const int* in_sizes, int n_in,
                              void* d_out, int out_size, void* d_ws, size_t ws_size,
                              hipStream_t stream) {
    const float* phi     = (const float*)d_in[0];
    const float* C_seq   = (const float*)d_in[1];
    const float* thK     = (const float*)d_in[2];
    const float* thQ     = (const float*)d_in[3];
    const float* W10     = (const float*)d_in[4];
    const float* b10     = (const float*)d_in[5];
    const float* W20     = (const float*)d_in[6];
    const float* b20     = (const float*)d_in[7];
    const float* log_eta = (const float*)d_in[8];

    const int T    = in_sizes[1];          // 8192
    const int dphi = in_sizes[0] / T;      // 4096

    float* u  = (float*)d_ws;                          // [T][128] = 4 MB
    float* dd = (float*)((char*)d_ws + (size_t)T * 128 * sizeof(float)); // [T][2]

    proj_kernel<<<T / 32, 256, 0, stream>>>(phi, thK, thQ, u, dphi);
    dots_kernel<<<T / 4, 256, 0, stream>>>(u, dd, T);
    ttt_scan<<<1, 256, 0, stream>>>(u, dd, C_seq, W10, b10, W20, b20, log_eta,
                                    (float*)d_out, T);
}

// Round 6
// 7614.728 us; speedup vs baseline: 2.5183x; 1.1455x over previous
//
#include <hip/hip_runtime.h>
#include <hip/hip_bf16.h>

#define DH 64
#define DM 256

__device__ __forceinline__ float tanh_fast(float y) {
    float e = __expf(2.0f * y);
    return 1.0f - 2.0f / (e + 1.0f);
}

__device__ __forceinline__ float sigmoid_fast(float x) {
    return 1.0f / (1.0f + __expf(-x));
}

// DPP butterfly sum over 64 lanes; total lands in lane 63.
template <int CTRL, int RMASK>
__device__ __forceinline__ float dpp_term(float x) {
    int p = __builtin_amdgcn_update_dpp(0, __float_as_int(x), CTRL, RMASK, 0xf, false);
    return __int_as_float(p);
}
__device__ __forceinline__ float wave_sum63(float x) {
    x += dpp_term<0xB1,  0xf>(x);
    x += dpp_term<0x4E,  0xf>(x);
    x += dpp_term<0x141, 0xf>(x);
    x += dpp_term<0x140, 0xf>(x);
    x += dpp_term<0x142, 0xa>(x);
    x += dpp_term<0x143, 0xc>(x);
    return x;
}

// ---------------------------------------------------------------------------
// Kernel A: u[t][0..63] = phi[t]·thetaQ[h], u[t][64..127] = phi[t]·thetaK[h]
// ---------------------------------------------------------------------------
__global__ __launch_bounds__(256) void proj_kernel(
    const float* __restrict__ phi,
    const float* __restrict__ thK,
    const float* __restrict__ thQ,
    float* __restrict__ u,
    int dphi)
{
    const int tid  = threadIdx.x;
    const int th32 = tid & 31;
    const int tt8  = tid >> 5;
    const int t0   = tt8 * 4;
    const int h0   = th32 * 4;
    const int T0   = blockIdx.x * 32;

    __shared__ float sPhiT[32][36];
    __shared__ float sThT[32][128];

    const int h   = tid >> 1;
    const int ko  = (tid & 1) * 16;
    const float* trow = (h < 64) ? (thQ + (size_t)h * dphi)
                                 : (thK + (size_t)(h - 64) * dphi);
    const int tr  = tid >> 3;
    const int k4p = (tid & 7) * 4;

    float4 pv, tv0, tv1, tv2, tv3;
    pv  = *(const float4*)&phi[(size_t)(T0 + tr) * dphi + k4p];
    tv0 = *(const float4*)&trow[ko + 0];
    tv1 = *(const float4*)&trow[ko + 4];
    tv2 = *(const float4*)&trow[ko + 8];
    tv3 = *(const float4*)&trow[ko + 12];

    float acc[4][4];
    #pragma unroll
    for (int i = 0; i < 4; ++i)
        #pragma unroll
        for (int jj = 0; jj < 4; ++jj) acc[i][jj] = 0.0f;

    const int NC = dphi / 32;
    for (int c = 0; c < NC; ++c) {
        __syncthreads();
        sPhiT[k4p + 0][tr] = pv.x;
        sPhiT[k4p + 1][tr] = pv.y;
        sPhiT[k4p + 2][tr] = pv.z;
        sPhiT[k4p + 3][tr] = pv.w;
        sThT[ko +  0][h] = tv0.x;  sThT[ko +  1][h] = tv0.y;
        sThT[ko +  2][h] = tv0.z;  sThT[ko +  3][h] = tv0.w;
        sThT[ko +  4][h] = tv1.x;  sThT[ko +  5][h] = tv1.y;
        sThT[ko +  6][h] = tv1.z;  sThT[ko +  7][h] = tv1.w;
        sThT[ko +  8][h] = tv2.x;  sThT[ko +  9][h] = tv2.y;
        sThT[ko + 10][h] = tv2.z;  sThT[ko + 11][h] = tv2.w;
        sThT[ko + 12][h] = tv3.x;  sThT[ko + 13][h] = tv3.y;
        sThT[ko + 14][h] = tv3.z;  sThT[ko + 15][h] = tv3.w;
        __syncthreads();
        if (c + 1 < NC) {
            const int kb = (c + 1) * 32;
            pv  = *(const float4*)&phi[(size_t)(T0 + tr) * dphi + kb + k4p];
            tv0 = *(const float4*)&trow[kb + ko + 0];
            tv1 = *(const float4*)&trow[kb + ko + 4];
            tv2 = *(const float4*)&trow[kb + ko + 8];
            tv3 = *(const float4*)&trow[kb + ko + 12];
        }
        #pragma unroll 8
        for (int k = 0; k < 32; ++k) {
            float4 ph = *(const float4*)&sPhiT[k][t0];
            float4 th = *(const float4*)&sThT[k][h0];
            acc[0][0] = fmaf(ph.x, th.x, acc[0][0]);
            acc[0][1] = fmaf(ph.x, th.y, acc[0][1]);
            acc[0][2] = fmaf(ph.x, th.z, acc[0][2]);
            acc[0][3] = fmaf(ph.x, th.w, acc[0][3]);
            acc[1][0] = fmaf(ph.y, th.x, acc[1][0]);
            acc[1][1] = fmaf(ph.y, th.y, acc[1][1]);
            acc[1][2] = fmaf(ph.y, th.z, acc[1][2]);
            acc[1][3] = fmaf(ph.y, th.w, acc[1][3]);
            acc[2][0] = fmaf(ph.z, th.x, acc[2][0]);
            acc[2][1] = fmaf(ph.z, th.y, acc[2][1]);
            acc[2][2] = fmaf(ph.z, th.z, acc[2][2]);
            acc[2][3] = fmaf(ph.z, th.w, acc[2][3]);
            acc[3][0] = fmaf(ph.w, th.x, acc[3][0]);
            acc[3][1] = fmaf(ph.w, th.y, acc[3][1]);
            acc[3][2] = fmaf(ph.w, th.z, acc[3][2]);
            acc[3][3] = fmaf(ph.w, th.w, acc[3][3]);
        }
    }
    #pragma unroll
    for (int i = 0; i < 4; ++i) {
        float4 o;
        o.x = acc[i][0]; o.y = acc[i][1]; o.z = acc[i][2]; o.w = acc[i][3];
        *(float4*)&u[(size_t)(T0 + t0 + i) * 128 + h0] = o;
    }
}

// ---------------------------------------------------------------------------
// Kernel A2: dd[t*2] = u_k(t)·u_q(t+1), dd[t*2+1] = u_k(t)·u_k(t+1)
// ---------------------------------------------------------------------------
__global__ __launch_bounds__(256) void dots_kernel(
    const float* __restrict__ u, float* __restrict__ dd, int T)
{
    const int t    = (blockIdx.x * 256 + threadIdx.x) >> 6;
    const int lane = threadIdx.x & 63;
    if (t >= T) return;
    float a = 0.f, q = 0.f, k = 0.f;
    if (t < T - 1) {
        a = u[(size_t)t * 128 + 64 + lane];
        q = u[(size_t)(t + 1) * 128 + lane];
        k = u[(size_t)(t + 1) * 128 + 64 + lane];
    }
    float p1 = a * q, p2 = a * k;
    #pragma unroll
    for (int off = 32; off > 0; off >>= 1) {
        p1 += __shfl_xor(p1, off);
        p2 += __shfl_xor(p2, off);
    }
    if (lane == 0) { dd[t * 2] = p1; dd[t * 2 + 1] = p2; }
}

// ---------------------------------------------------------------------------
// Kernel B: sequential TTT scan, i-split matvec across the 4 waves.
// Wave w owns W1 rows [16w,16w+16) x all 256 cols (lane: 16x4 tile).
// Per step: phase B finishes z(t) from exchanged partials (+1-step-deferral
// fixup via precomputed dots), computes activations + e~1; phase C issues the
// next-step matvec (overlaps the sigmoid/dZ2 chain), applies the W1 update,
// writes partials(t+1). Broadcast LDS traffic drops 16x vs full-row reads.
// ---------------------------------------------------------------------------

#define PBQ(pb, w, jj) pbuf[(((pb)*4 + (w))*2 + 0)*256 + (jj)]
#define PBK(pb, w, jj) pbuf[(((pb)*4 + (w))*2 + 1)*256 + (jj)]

#define MV1(qs, ks, ii) do {                                                \
    float4 wrow_ = w1r[ii];                                                 \
    aq4_.x = fmaf((qs), wrow_.x, aq4_.x);                                   \
    aq4_.y = fmaf((qs), wrow_.y, aq4_.y);                                   \
    aq4_.z = fmaf((qs), wrow_.z, aq4_.z);                                   \
    aq4_.w = fmaf((qs), wrow_.w, aq4_.w);                                   \
    ak4_.x = fmaf((ks), wrow_.x, ak4_.x);                                   \
    ak4_.y = fmaf((ks), wrow_.y, ak4_.y);                                   \
    ak4_.z = fmaf((ks), wrow_.z, ak4_.z);                                   \
    ak4_.w = fmaf((ks), wrow_.w, ak4_.w);                                   \
} while (0)
#define MV4(qv, kv, b) do {                                                 \
    MV1((qv).x, (kv).x, (b) + 0); MV1((qv).y, (kv).y, (b) + 1);             \
    MV1((qv).z, (kv).z, (b) + 2); MV1((qv).w, (kv).w, (b) + 3);             \
} while (0)
#define UPD1(uks, ii) do {                                                  \
    float4 wr_ = w1r[ii];                                                   \
    wr_.x = fmaf(-(uks), e1g_.x, wr_.x);                                    \
    wr_.y = fmaf(-(uks), e1g_.y, wr_.y);                                    \
    wr_.z = fmaf(-(uks), e1g_.z, wr_.z);                                    \
    wr_.w = fmaf(-(uks), e1g_.w, wr_.w);                                    \
    w1r[ii] = wr_;                                                          \
} while (0)

#define STEP(t_, KC, KN) do {                                               \
    const int r_  = (t_) & 63;                                              \
    const int B_  = (t_) >> 6;                                              \
    const int bs_ = B_ & 1;                                                 \
    const int pb_ = (t_) & 1;                                               \
    /* ---- phase B ---- */                                                 \
    float zqs_ = ((PBQ(pb_,0,j) + PBQ(pb_,1,j)) +                           \
                  (PBQ(pb_,2,j) + PBQ(pb_,3,j)));                           \
    float zks_ = ((PBK(pb_,0,j) + PBK(pb_,1,j)) +                           \
                  (PBK(pb_,2,j) + PBK(pb_,3,j)));                           \
    const int tm1_ = ((t_) >= 1) ? (t_) - 1 : 0;                            \
    float2 dd1_ = *(const float2*)&dbuf[((tm1_ >> 6) & 1)*128 +             \
                                        (tm1_ & 63)*2];                     \
    float zq_ = zqs_ + b1j - e1p * dd1_.x;                                  \
    float zk_ = zks_ + b1j - e1p * dd1_.y;                                  \
    float tk_ = tanh_fast(0.79788456f * zk_ * fmaf(0.044715f, zk_*zk_, 1.f));\
    float x2_ = 0.5f * zk_ * (1.f + tk_);                                   \
    float tq_ = tanh_fast(0.79788456f * zq_ * fmaf(0.044715f, zq_*zq_, 1.f));\
    float aq_ = 0.5f * zq_ * (1.f + tq_);                                   \
    float gb_ = 0.5f * zk_ * ((1.f - tk_*tk_) *                             \
                fmaf(0.1070322243f, zk_*zk_, 0.79788456f))                  \
              + 0.5f * (1.f + tk_);                                         \
    float et1_ = eta * w2j * gb_;                                           \
    float pq_ = wave_sum63(aq_ * w2j);                                      \
    float pk_ = wave_sum63(x2_ * w2j);                                      \
    if (lane == 63) { pqk[pb_][0][wv] = pq_; pqk[pb_][1][wv] = pk_; }       \
    ebuf[j] = et1_;                                                         \
    asm volatile("s_waitcnt lgkmcnt(0)" ::: "memory");                      \
    __builtin_amdgcn_s_barrier();                                           \
    asm volatile("" ::: "memory");                                          \
    /* ---- phase C ---- */                                                 \
    const int rn_ = ((t_) + 1 < T) ? (t_) + 1 : (t_);                       \
    const float* urow_ = &ubuf[((rn_ >> 6) & 1)*8192 + (rn_ & 63)*128];     \
    float4 uq0_ = *(const float4*)&urow_[uqo +  0];                         \
    float4 uq1_ = *(const float4*)&urow_[uqo +  4];                         \
    float4 uq2_ = *(const float4*)&urow_[uqo +  8];                         \
    float4 uq3_ = *(const float4*)&urow_[uqo + 12];                         \
    KN[0] = *(const float4*)&urow_[uko +  0];                               \
    KN[1] = *(const float4*)&urow_[uko +  4];                               \
    KN[2] = *(const float4*)&urow_[uko +  8];                               \
    KN[3] = *(const float4*)&urow_[uko + 12];                               \
    float4 aq4_ = make_float4(0.f, 0.f, 0.f, 0.f);                          \
    float4 ak4_ = make_float4(0.f, 0.f, 0.f, 0.f);                          \
    MV4(uq0_, KN[0], 0);  MV4(uq1_, KN[1], 4);                              \
    MV4(uq2_, KN[2], 8);  MV4(uq3_, KN[3], 12);                             \
    float4 pq4_ = *(const float4*)&pqk[pb_][0][0];                          \
    float4 pk4_ = *(const float4*)&pqk[pb_][1][0];                          \
    float zs_ = ((pq4_.x + pq4_.y) + (pq4_.z + pq4_.w)) + b2;               \
    float zp_ = ((pk4_.x + pk4_.y) + (pk4_.z + pk4_.w)) + b2;               \
    float s_    = sigmoid_fast(zs_);                                        \
    float pred_ = sigmoid_fast(zp_);                                        \
    float dZ2_  = 2.f * pred_ * pred_ * (1.f - pred_);                      \
    float4 eg_  = *(const float4*)&ebuf[lane * 4];                          \
    float4 e1g_;                                                            \
    e1g_.x = dZ2_ * eg_.x; e1g_.y = dZ2_ * eg_.y;                           \
    e1g_.z = dZ2_ * eg_.z; e1g_.w = dZ2_ * eg_.w;                           \
    UPD1(KC[0].x,  0); UPD1(KC[0].y,  1); UPD1(KC[0].z,  2); UPD1(KC[0].w,  3); \
    UPD1(KC[1].x,  4); UPD1(KC[1].y,  5); UPD1(KC[1].z,  6); UPD1(KC[1].w,  7); \
    UPD1(KC[2].x,  8); UPD1(KC[2].y,  9); UPD1(KC[2].z, 10); UPD1(KC[2].w, 11); \
    UPD1(KC[3].x, 12); UPD1(KC[3].y, 13); UPD1(KC[3].z, 14); UPD1(KC[3].w, 15); \
    *(float4*)&PBQ(pb_ ^ 1, wv, lane * 4) = aq4_;                           \
    *(float4*)&PBK(pb_ ^ 1, wv, lane * 4) = ak4_;                           \
    float e1j_ = dZ2_ * et1_;                                               \
    b1j -= e1j_;                                                            \
    w2j  = fmaf(-eta * dZ2_, x2_, w2j);                                     \
    b2  -= eta * dZ2_;                                                      \
    e1p  = e1j_;                                                            \
    float c_ = cbuf[bs_ * 64 + r_];                                         \
    if (j == 0) out[t_] = s_;                                               \
    float df_ = s_ - c_;                                                    \
    loss = fmaf(df_, df_, loss);                                            \
    if (r_ == 0 && B_ + 1 < NB) {                                           \
        const float* src_ = u + (size_t)(B_ + 1) * 8192;                    \
        _Pragma("unroll")                                                   \
        for (int q_ = 0; q_ < 8; ++q_)                                      \
            st[q_] = *(const float4*)&src_[q_ * 1024 + j * 4];              \
        if (j < 16) stc = *(const float4*)&C_seq[(B_ + 1) * 64 + j * 4];    \
        if (j >= 32 && j < 64)                                              \
            std = *(const float4*)&dd_g[(B_ + 1) * 128 + (j - 32) * 4];     \
    }                                                                       \
    if (r_ == 32 && B_ + 1 < NB) {                                          \
        _Pragma("unroll")                                                   \
        for (int q_ = 0; q_ < 8; ++q_)                                      \
            *(float4*)&ubuf[(bs_ ^ 1)*8192 + q_ * 1024 + j * 4] = st[q_];   \
        if (j < 16) *(float4*)&cbuf[(bs_ ^ 1)*64 + j * 4] = stc;            \
        if (j >= 32 && j < 64)                                              \
            *(float4*)&dbuf[(bs_ ^ 1)*128 + (j - 32) * 4] = std;            \
    }                                                                       \
    asm volatile("s_waitcnt lgkmcnt(0)" ::: "memory");                      \
    __builtin_amdgcn_s_barrier();                                           \
    asm volatile("" ::: "memory");                                          \
} while (0)

__global__ __launch_bounds__(256, 1) void ttt_scan(
    const float* __restrict__ u,       // [T][128]
    const float* __restrict__ dd_g,    // [T][2]
    const float* __restrict__ C_seq,   // [T]
    const float* __restrict__ W10,     // [64][256]
    const float* __restrict__ b10,     // [256]
    const float* __restrict__ W20,     // [256]
    const float* __restrict__ b20,     // [1]
    const float* __restrict__ log_eta, // [1]
    float* __restrict__ out,           // [T+1]
    int T)
{
    const int j    = threadIdx.x;
    const int lane = j & 63;
    const int wv   = j >> 6;
    const int uqo  = 16 * wv;
    const int uko  = 64 + 16 * wv;

    // wave wv owns W1 rows [16wv,16wv+16); lane owns cols [4*lane,4*lane+4)
    float4 w1r[16];
    #pragma unroll
    for (int i = 0; i < 16; ++i)
        w1r[i] = *(const float4*)&W10[(16 * wv + i) * DM + lane * 4];
    float b1j = b10[j];
    float w2j = W20[j];
    float b2  = b20[0];
    const float eta = __expf(log_eta[0]);
    float loss = 0.0f;
    float e1p  = 0.0f;

    __shared__ __align__(16) float ubuf[2 * 8192];    // 64 KB
    __shared__ __align__(16) float pbuf[2 * 4 * 2 * 256]; // 16 KB
    __shared__ __align__(16) float cbuf[2 * 64];
    __shared__ __align__(16) float dbuf[2 * 128];
    __shared__ __align__(16) float ebuf[256];
    __shared__ __align__(16) float pqk[2][2][4];

    const int NB = T >> 6;

    // prologue: stage block 0
    #pragma unroll
    for (int q = 0; q < 8; ++q) {
        float4 v = *(const float4*)&u[q * 1024 + j * 4];
        *(float4*)&ubuf[q * 1024 + j * 4] = v;
    }
    if (j < 16) {
        float4 c4 = *(const float4*)&C_seq[j * 4];
        *(float4*)&cbuf[j * 4] = c4;
    }
    if (j >= 32 && j < 64) {
        float4 d4 = *(const float4*)&dd_g[(j - 32) * 4];
        *(float4*)&dbuf[(j - 32) * 4] = d4;
    }
    __syncthreads();

    float4 kcA[4], kcB[4];
    float4 st[8];
    float4 stc = make_float4(0.f, 0.f, 0.f, 0.f);
    float4 std = make_float4(0.f, 0.f, 0.f, 0.f);

    // peel: partials(0) = u(0)·W1(0)
    {
        const float* urow_ = &ubuf[0];
        float4 uq0_ = *(const float4*)&urow_[uqo +  0];
        float4 uq1_ = *(const float4*)&urow_[uqo +  4];
        float4 uq2_ = *(const float4*)&urow_[uqo +  8];
        float4 uq3_ = *(const float4*)&urow_[uqo + 12];
        kcA[0] = *(const float4*)&urow_[uko +  0];
        kcA[1] = *(const float4*)&urow_[uko +  4];
        kcA[2] = *(const float4*)&urow_[uko +  8];
        kcA[3] = *(const float4*)&urow_[uko + 12];
        float4 aq4_ = make_float4(0.f, 0.f, 0.f, 0.f);
        float4 ak4_ = make_float4(0.f, 0.f, 0.f, 0.f);
        MV4(uq0_, kcA[0], 0);  MV4(uq1_, kcA[1], 4);
        MV4(uq2_, kcA[2], 8);  MV4(uq3_, kcA[3], 12);
        *(float4*)&PBQ(0, wv, lane * 4) = aq4_;
        *(float4*)&PBK(0, wv, lane * 4) = ak4_;
    }
    __syncthreads();

    for (int t = 0; t < T; t += 2) {
        STEP(t,     kcA, kcB);
        STEP(t + 1, kcB, kcA);
    }
    if (j == 0) out[T] = loss;
}

// ---------------------------------------------------------------------------
extern "C" void kernel_launch(void* const* d_in, const int* in_sizes, int n_in,
                              void* d_out, int out_size, void* d_ws, size_t ws_size,
                              hipStream_t stream) {
    const float* phi     = (const float*)d_in[0];
    const float* C_seq   = (const float*)d_in[1];
    const float* thK     = (const float*)d_in[2];
    const float* thQ     = (const float*)d_in[3];
    const float* W10     = (const float*)d_in[4];
    const float* b10     = (const float*)d_in[5];
    const float* W20     = (const float*)d_in[6];
    const float* b20     = (const float*)d_in[7];
    const float* log_eta = (const float*)d_in[8];

    const int T    = in_sizes[1];          // 8192
    const int dphi = in_sizes[0] / T;      // 4096

    float* u  = (float*)d_ws;                                            // [T][128]
    float* dd = (float*)((char*)d_ws + (size_t)T * 128 * sizeof(float)); // [T][2]

    proj_kernel<<<T / 32, 256, 0, stream>>>(phi, thK, thQ, u, dphi);
    dots_kernel<<<T / 4, 256, 0, stream>>>(u, dd, T);
    ttt_scan<<<1, 256, 0, stream>>>(u, dd, C_seq, W10, b10, W20, b20, log_eta,
                                    (float*)d_out, T);
}

// Round 7
// 6438.551 us; speedup vs baseline: 2.9784x; 1.1827x over previous
//
#include <hip/hip_runtime.h>
#include <hip/hip_bf16.h>

#define DH 64
#define DM 256

typedef float f32x2 __attribute__((ext_vector_type(2)));

__device__ __forceinline__ f32x2 sp2(float s) { return (f32x2){s, s}; }
__device__ __forceinline__ f32x2 pkfma(f32x2 a, f32x2 b, f32x2 c) {
#if __has_builtin(__builtin_elementwise_fma)
    return __builtin_elementwise_fma(a, b, c);
#else
    f32x2 r; r.x = fmaf(a.x, b.x, c.x); r.y = fmaf(a.y, b.y, c.y); return r;
#endif
}

__device__ __forceinline__ float tanh_fast(float y) {
    float e = __expf(2.0f * y);
    return 1.0f - 2.0f / (e + 1.0f);
}
__device__ __forceinline__ float sigmoid_fast(float x) {
    return 1.0f / (1.0f + __expf(-x));
}

// DPP butterfly sum over 64 lanes; total lands in lane 63.
template <int CTRL, int RMASK>
__device__ __forceinline__ float dpp_term(float x) {
    int p = __builtin_amdgcn_update_dpp(0, __float_as_int(x), CTRL, RMASK, 0xf, false);
    return __int_as_float(p);
}
__device__ __forceinline__ float wave_sum63(float x) {
    x += dpp_term<0xB1,  0xf>(x);
    x += dpp_term<0x4E,  0xf>(x);
    x += dpp_term<0x141, 0xf>(x);
    x += dpp_term<0x140, 0xf>(x);
    x += dpp_term<0x142, 0xa>(x);
    x += dpp_term<0x143, 0xc>(x);
    return x;
}

// ---------------------------------------------------------------------------
// Kernel A: u[t][0..63] = phi[t]·thetaQ[h], u[t][64..127] = phi[t]·thetaK[h]
// ---------------------------------------------------------------------------
__global__ __launch_bounds__(256) void proj_kernel(
    const float* __restrict__ phi,
    const float* __restrict__ thK,
    const float* __restrict__ thQ,
    float* __restrict__ u,
    int dphi)
{
    const int tid  = threadIdx.x;
    const int th32 = tid & 31;
    const int tt8  = tid >> 5;
    const int t0   = tt8 * 4;
    const int h0   = th32 * 4;
    const int T0   = blockIdx.x * 32;

    __shared__ float sPhiT[32][36];
    __shared__ float sThT[32][128];

    const int h   = tid >> 1;
    const int ko  = (tid & 1) * 16;
    const float* trow = (h < 64) ? (thQ + (size_t)h * dphi)
                                 : (thK + (size_t)(h - 64) * dphi);
    const int tr  = tid >> 3;
    const int k4p = (tid & 7) * 4;

    float4 pv, tv0, tv1, tv2, tv3;
    pv  = *(const float4*)&phi[(size_t)(T0 + tr) * dphi + k4p];
    tv0 = *(const float4*)&trow[ko + 0];
    tv1 = *(const float4*)&trow[ko + 4];
    tv2 = *(const float4*)&trow[ko + 8];
    tv3 = *(const float4*)&trow[ko + 12];

    float acc[4][4];
    #pragma unroll
    for (int i = 0; i < 4; ++i)
        #pragma unroll
        for (int jj = 0; jj < 4; ++jj) acc[i][jj] = 0.0f;

    const int NC = dphi / 32;
    for (int c = 0; c < NC; ++c) {
        __syncthreads();
        sPhiT[k4p + 0][tr] = pv.x;
        sPhiT[k4p + 1][tr] = pv.y;
        sPhiT[k4p + 2][tr] = pv.z;
        sPhiT[k4p + 3][tr] = pv.w;
        sThT[ko +  0][h] = tv0.x;  sThT[ko +  1][h] = tv0.y;
        sThT[ko +  2][h] = tv0.z;  sThT[ko +  3][h] = tv0.w;
        sThT[ko +  4][h] = tv1.x;  sThT[ko +  5][h] = tv1.y;
        sThT[ko +  6][h] = tv1.z;  sThT[ko +  7][h] = tv1.w;
        sThT[ko +  8][h] = tv2.x;  sThT[ko +  9][h] = tv2.y;
        sThT[ko + 10][h] = tv2.z;  sThT[ko + 11][h] = tv2.w;
        sThT[ko + 12][h] = tv3.x;  sThT[ko + 13][h] = tv3.y;
        sThT[ko + 14][h] = tv3.z;  sThT[ko + 15][h] = tv3.w;
        __syncthreads();
        if (c + 1 < NC) {
            const int kb = (c + 1) * 32;
            pv  = *(const float4*)&phi[(size_t)(T0 + tr) * dphi + kb + k4p];
            tv0 = *(const float4*)&trow[kb + ko + 0];
            tv1 = *(const float4*)&trow[kb + ko + 4];
            tv2 = *(const float4*)&trow[kb + ko + 8];
            tv3 = *(const float4*)&trow[kb + ko + 12];
        }
        #pragma unroll 8
        for (int k = 0; k < 32; ++k) {
            float4 ph = *(const float4*)&sPhiT[k][t0];
            float4 th = *(const float4*)&sThT[k][h0];
            acc[0][0] = fmaf(ph.x, th.x, acc[0][0]);
            acc[0][1] = fmaf(ph.x, th.y, acc[0][1]);
            acc[0][2] = fmaf(ph.x, th.z, acc[0][2]);
            acc[0][3] = fmaf(ph.x, th.w, acc[0][3]);
            acc[1][0] = fmaf(ph.y, th.x, acc[1][0]);
            acc[1][1] = fmaf(ph.y, th.y, acc[1][1]);
            acc[1][2] = fmaf(ph.y, th.z, acc[1][2]);
            acc[1][3] = fmaf(ph.y, th.w, acc[1][3]);
            acc[2][0] = fmaf(ph.z, th.x, acc[2][0]);
            acc[2][1] = fmaf(ph.z, th.y, acc[2][1]);
            acc[2][2] = fmaf(ph.z, th.z, acc[2][2]);
            acc[2][3] = fmaf(ph.z, th.w, acc[2][3]);
            acc[3][0] = fmaf(ph.w, th.x, acc[3][0]);
            acc[3][1] = fmaf(ph.w, th.y, acc[3][1]);
            acc[3][2] = fmaf(ph.w, th.z, acc[3][2]);
            acc[3][3] = fmaf(ph.w, th.w, acc[3][3]);
        }
    }
    #pragma unroll
    for (int i = 0; i < 4; ++i) {
        float4 o;
        o.x = acc[i][0]; o.y = acc[i][1]; o.z = acc[i][2]; o.w = acc[i][3];
        *(float4*)&u[(size_t)(T0 + t0 + i) * 128 + h0] = o;
    }
}

// ---------------------------------------------------------------------------
// Kernel A2: dd4[t] = { uk(t-1)·uq(t), uk(t-1)·uk(t),
//                       uk(t-2)·uq(t), uk(t-2)·uk(t) }   (zeros at edges)
// ---------------------------------------------------------------------------
__global__ __launch_bounds__(256) void dots_kernel(
    const float* __restrict__ u, float4* __restrict__ dd4, int T)
{
    const int t    = (blockIdx.x * 256 + threadIdx.x) >> 6;
    const int lane = threadIdx.x & 63;
    if (t >= T) return;
    float uq = u[(size_t)t * 128 + lane];
    float uk = u[(size_t)t * 128 + 64 + lane];
    float k1 = (t >= 1) ? u[(size_t)(t - 1) * 128 + 64 + lane] : 0.f;
    float k2 = (t >= 2) ? u[(size_t)(t - 2) * 128 + 64 + lane] : 0.f;
    float a = k1 * uq, b = k1 * uk, c = k2 * uq, d = k2 * uk;
    #pragma unroll
    for (int off = 32; off > 0; off >>= 1) {
        a += __shfl_xor(a, off);
        b += __shfl_xor(b, off);
        c += __shfl_xor(c, off);
        d += __shfl_xor(d, off);
    }
    if (lane == 0) dd4[t] = make_float4(a, b, c, d);
}

// ---------------------------------------------------------------------------
// Kernel B: sequential TTT scan — ONE barrier per step, depth-2 deferral.
// At iter t:   w1r = W1(t-2);  UPD applies e1(t-2) (all inputs known at iter
// top -> fills stalls), MV computes P(t+1)=u(t+1)·W1(t-1);
// z(t) = P(t)+b1(t) - e1(t-2)·dot2 - e1(t-1)·dot1 (dots precomputed);
// scalar chain finishes step t-1 (pqk partials from last iter).
// MV/UPD in packed fp32 (v_pk_fma_f32).
// ---------------------------------------------------------------------------

#define ROWU(uqs, uks, ums, i2) do {                                         \
    f32x2 wa_ = pkfma(sp2(-(ums)), e1g0_, w1p[i2]);                          \
    f32x2 wb_ = pkfma(sp2(-(ums)), e1g1_, w1p[(i2) + 1]);                    \
    w1p[i2] = wa_; w1p[(i2) + 1] = wb_;                                      \
    aq0_ = pkfma(sp2(uqs), wa_, aq0_);  aq1_ = pkfma(sp2(uqs), wb_, aq1_);   \
    ak0_ = pkfma(sp2(uks), wa_, ak0_);  ak1_ = pkfma(sp2(uks), wb_, ak1_);   \
} while (0)
#define ROWU4(q4, k4, m4, b) do {                                            \
    ROWU((q4).x, (k4).x, (m4).x, (b) + 0);                                   \
    ROWU((q4).y, (k4).y, (m4).y, (b) + 2);                                   \
    ROWU((q4).z, (k4).z, (m4).z, (b) + 4);                                   \
    ROWU((q4).w, (k4).w, (m4).w, (b) + 6);                                   \
} while (0)
#define ROWM(uqs, uks, i2) do {                                              \
    aq0_ = pkfma(sp2(uqs), w1p[i2], aq0_);                                   \
    aq1_ = pkfma(sp2(uqs), w1p[(i2) + 1], aq1_);                             \
    ak0_ = pkfma(sp2(uks), w1p[i2], ak0_);                                   \
    ak1_ = pkfma(sp2(uks), w1p[(i2) + 1], ak1_);                             \
} while (0)
#define ROWM4(q4, k4, b) do {                                                \
    ROWM((q4).x, (k4).x, (b) + 0);                                           \
    ROWM((q4).y, (k4).y, (b) + 2);                                           \
    ROWM((q4).z, (k4).z, (b) + 4);                                           \
    ROWM((q4).w, (k4).w, (b) + 6);                                           \
} while (0)

#define STEP(t_) do {                                                        \
    const int pbR_ = (t_) & 1;                                               \
    const int r_   = (t_) & 63;                                              \
    const int B_   = (t_) >> 6;                                              \
    const int bs_  = B_ & 1;                                                 \
    /* LDS reads (issued early) */                                           \
    float4 pqQ_ = *(const float4*)&pqk[pbR_ ^ 1][0];                         \
    float4 pqK_ = *(const float4*)&pqk[pbR_ ^ 1][4];                         \
    const int sE_ = ((t_) + 2) & 3;                                          \
    float eb0_ = ebufT[sE_][0][lane];                                        \
    float eb1_ = ebufT[sE_][1][lane];                                        \
    float eb2_ = ebufT[sE_][2][lane];                                        \
    float eb3_ = ebufT[sE_][3][lane];                                        \
    float4 ddv_ = *(const float4*)&dbuf[bs_][r_][0];                         \
    float pA0_ = pbuf[pbR_][0][0][j], pA1_ = pbuf[pbR_][1][0][j];            \
    float pA2_ = pbuf[pbR_][2][0][j], pA3_ = pbuf[pbR_][3][0][j];            \
    float pB0_ = pbuf[pbR_][0][1][j], pB1_ = pbuf[pbR_][1][1][j];            \
    float pB2_ = pbuf[pbR_][2][1][j], pB3_ = pbuf[pbR_][3][1][j];            \
    const int ci_ = ((t_) > 0) ? (t_) - 1 : 0;                               \
    float cv_ = cbuf[((ci_ >> 6) & 1) * 64 + (ci_ & 63)];                    \
    const int rn_ = ((t_) + 1 < T) ? (t_) + 1 : T - 1;                       \
    const float* urN_ = &ubuf[((rn_ >> 6) & 1) * 8192 + (rn_ & 63) * 128];   \
    float4 q40_ = *(const float4*)&urN_[uqo +  0];                           \
    float4 q41_ = *(const float4*)&urN_[uqo +  4];                           \
    float4 q42_ = *(const float4*)&urN_[uqo +  8];                           \
    float4 q43_ = *(const float4*)&urN_[uqo + 12];                           \
    float4 k40_ = *(const float4*)&urN_[uko +  0];                           \
    float4 k41_ = *(const float4*)&urN_[uko +  4];                           \
    float4 k42_ = *(const float4*)&urN_[uko +  8];                           \
    float4 k43_ = *(const float4*)&urN_[uko + 12];                           \
    const int tm2_ = ((t_) >= 2) ? (t_) - 2 : 0;                             \
    const float* urM_ = &ubuf[((tm2_ >> 6) & 1) * 8192 + (tm2_ & 63) * 128]; \
    float4 m40_ = *(const float4*)&urM_[uko +  0];                           \
    float4 m41_ = *(const float4*)&urM_[uko +  4];                           \
    float4 m42_ = *(const float4*)&urM_[uko +  8];                           \
    float4 m43_ = *(const float4*)&urM_[uko + 12];                           \
    /* chain head: finish step t-1 */                                        \
    float zs_ = ((pqQ_.x + pqQ_.y) + (pqQ_.z + pqQ_.w)) + b2;                \
    float zp_ = ((pqK_.x + pqK_.y) + (pqK_.z + pqK_.w)) + b2;                \
    float s_    = sigmoid_fast(zs_);                                         \
    float pred_ = sigmoid_fast(zp_);                                         \
    float dZ2_  = 2.f * pred_ * pred_ * (1.f - pred_);                       \
    /* off-chain: UPD (e1(t-2), via dZ2p) fused with MV(t+1) */              \
    f32x2 e1g0_ = sp2(dZ2p) * (f32x2){eb0_, eb1_};                           \
    f32x2 e1g1_ = sp2(dZ2p) * (f32x2){eb2_, eb3_};                           \
    f32x2 aq0_ = sp2(0.f), aq1_ = sp2(0.f), ak0_ = sp2(0.f), ak1_ = sp2(0.f);\
    ROWU4(q40_, k40_, m40_, 0);                                              \
    ROWU4(q41_, k41_, m41_, 8);                                              \
    ROWU4(q42_, k42_, m42_, 16);                                             \
    ROWU4(q43_, k43_, m43_, 24);                                             \
    { float4 wq_; wq_.x = aq0_.x; wq_.y = aq0_.y; wq_.z = aq1_.x; wq_.w = aq1_.y; \
      *(float4*)&pbuf[pbR_ ^ 1][wv][0][lane * 4] = wq_;                      \
      float4 wk_; wk_.x = ak0_.x; wk_.y = ak0_.y; wk_.z = ak1_.x; wk_.w = ak1_.y; \
      *(float4*)&pbuf[pbR_ ^ 1][wv][1][lane * 4] = wk_; }                    \
    /* scalar state + z(t) */                                                \
    float e1o_  = dZ2_ * en1;                                                \
    float e1o2_ = dZ2p * en2;                                                \
    b1j -= e1o_;                                                             \
    w2j  = fmaf(-eta * dZ2_, x2p, w2j);                                      \
    b2  -= eta * dZ2_;                                                       \
    float Pq_ = ((pA0_ + pA1_) + (pA2_ + pA3_));                             \
    float Pk_ = ((pB0_ + pB1_) + (pB2_ + pB3_));                             \
    float zq_ = Pq_ + b1j - e1o2_ * ddv_.z - e1o_ * ddv_.x;                  \
    float zk_ = Pk_ + b1j - e1o2_ * ddv_.w - e1o_ * ddv_.y;                  \
    float tk_ = tanh_fast(0.79788456f * zk_ * fmaf(0.044715f, zk_*zk_, 1.f));\
    float x2_ = 0.5f * zk_ * (1.f + tk_);                                    \
    float tq_ = tanh_fast(0.79788456f * zq_ * fmaf(0.044715f, zq_*zq_, 1.f));\
    float aq_ = 0.5f * zq_ * (1.f + tq_);                                    \
    float gb_ = 0.5f * zk_ * ((1.f - tk_*tk_) *                              \
                fmaf(0.1070322243f, zk_*zk_, 0.79788456f))                   \
              + 0.5f * (1.f + tk_);                                          \
    float en_ = eta * w2j * gb_;                                             \
    ebufT[(t_) & 3][j & 3][j >> 2] = en_;                                    \
    float pqs_ = wave_sum63(aq_ * w2j);                                      \
    float pks_ = wave_sum63(x2_ * w2j);                                      \
    if (lane == 63) { pqk[(t_) & 1][wv] = pqs_; pqk[(t_) & 1][4 + wv] = pks_; } \
    if ((t_) > 0) {                                                          \
        if (j == 0) out[(t_) - 1] = s_;                                      \
        float df_ = s_ - cv_;                                                \
        loss = fmaf(df_, df_, loss);                                         \
    }                                                                        \
    dZ2p = dZ2_; en2 = en1; en1 = en_; x2p = x2_;                            \
    if (r_ == 0 && B_ + 1 < NB) {                                            \
        const float* src_ = u + (size_t)(B_ + 1) * 8192;                     \
        _Pragma("unroll")                                                    \
        for (int q_ = 0; q_ < 8; ++q_)                                       \
            st[q_] = *(const float4*)&src_[q_ * 1024 + j * 4];               \
        if (j < 16) stc = *(const float4*)&C_seq[(B_ + 1) * 64 + j * 4];     \
        if (j < 64) std = dd_g4[(B_ + 1) * 64 + j];                          \
    }                                                                        \
    if (r_ == 32 && B_ + 1 < NB) {                                           \
        _Pragma("unroll")                                                    \
        for (int q_ = 0; q_ < 8; ++q_)                                       \
            *(float4*)&ubuf[(bs_ ^ 1) * 8192 + q_ * 1024 + j * 4] = st[q_];  \
        if (j < 16) *(float4*)&cbuf[(bs_ ^ 1) * 64 + j * 4] = stc;           \
        if (j < 64) *(float4*)&dbuf[bs_ ^ 1][j][0] = std;                    \
    }                                                                        \
    asm volatile("s_waitcnt lgkmcnt(0)" ::: "memory");                       \
    __builtin_amdgcn_s_barrier();                                            \
    asm volatile("" ::: "memory");                                           \
} while (0)

__global__ __launch_bounds__(256, 1) void ttt_scan(
    const float* __restrict__ u,       // [T][128]
    const float4* __restrict__ dd_g4,  // [T] lag-1/lag-2 dots
    const float* __restrict__ C_seq,   // [T]
    const float* __restrict__ W10,     // [64][256]
    const float* __restrict__ b10,     // [256]
    const float* __restrict__ W20,     // [256]
    const float* __restrict__ b20,     // [1]
    const float* __restrict__ log_eta, // [1]
    float* __restrict__ out,           // [T+1]
    int T)
{
    const int j    = threadIdx.x;
    const int lane = j & 63;
    const int wv   = j >> 6;
    const int uqo  = 16 * wv;
    const int uko  = 64 + 16 * wv;

    __shared__ __align__(16) float ubuf[2 * 8192];       // 64 KB
    __shared__ __align__(16) float pbuf[2][4][2][256];   // 16 KB
    __shared__ __align__(16) float ebufT[4][4][72];      // 4.6 KB
    __shared__ __align__(16) float pqk[2][8];
    __shared__ __align__(16) float cbuf[2 * 64];
    __shared__ __align__(16) float dbuf[2][64][4];       // 2 KB

    const int NB = T >> 6;

    // ---- prologue staging ----
    #pragma unroll
    for (int q = 0; q < 8; ++q) {
        float4 v = *(const float4*)&u[q * 1024 + j * 4];
        *(float4*)&ubuf[q * 1024 + j * 4] = v;
    }
    if (j < 16) {
        float4 c4 = *(const float4*)&C_seq[j * 4];
        *(float4*)&cbuf[j * 4] = c4;
    }
    if (j < 64) *(float4*)&dbuf[0][j][0] = dd_g4[j];
    if (j < 8)  pqk[1][j] = -2.5e29f;          // step "-1": pred = 0, dZ2 = 0
    {
        float* ez = &ebufT[2][0][0];           // zero slots 2,3 (e~1(-2),(-1))
        for (int k = j; k < 2 * 4 * 72; k += 256) ez[k] = 0.f;
    }
    __syncthreads();

    // wave wv owns W1 rows [16wv,16wv+16); lane owns cols [4*lane,4*lane+4)
    f32x2 w1p[32];
    #pragma unroll
    for (int i = 0; i < 16; ++i) {
        float4 wr = *(const float4*)&W10[(16 * wv + i) * DM + lane * 4];
        w1p[2 * i]     = (f32x2){wr.x, wr.y};
        w1p[2 * i + 1] = (f32x2){wr.z, wr.w};
    }
    float b1j = b10[j];
    float w2j = W20[j];
    float b2  = b20[0];
    const float eta = __expf(log_eta[0]);
    float loss = 0.0f;
    float dZ2p = 0.0f, en1 = 0.0f, en2 = 0.0f, x2p = 0.0f;

    float4 st[8];
    float4 stc = make_float4(0.f, 0.f, 0.f, 0.f);
    float4 std = make_float4(0.f, 0.f, 0.f, 0.f);

    // peel: pbuf(0) = u(0)·W1(0)
    {
        const float* ur0 = &ubuf[0];
        float4 q40 = *(const float4*)&ur0[uqo +  0];
        float4 q41 = *(const float4*)&ur0[uqo +  4];
        float4 q42 = *(const float4*)&ur0[uqo +  8];
        float4 q43 = *(const float4*)&ur0[uqo + 12];
        float4 k40 = *(const float4*)&ur0[uko +  0];
        float4 k41 = *(const float4*)&ur0[uko +  4];
        float4 k42 = *(const float4*)&ur0[uko +  8];
        float4 k43 = *(const float4*)&ur0[uko + 12];
        f32x2 aq0_ = sp2(0.f), aq1_ = sp2(0.f), ak0_ = sp2(0.f), ak1_ = sp2(0.f);
        ROWM4(q40, k40, 0);
        ROWM4(q41, k41, 8);
        ROWM4(q42, k42, 16);
        ROWM4(q43, k43, 24);
        float4 wq; wq.x = aq0_.x; wq.y = aq0_.y; wq.z = aq1_.x; wq.w = aq1_.y;
        *(float4*)&pbuf[0][wv][0][lane * 4] = wq;
        float4 wk; wk.x = ak0_.x; wk.y = ak0_.y; wk.z = ak1_.x; wk.w = ak1_.y;
        *(float4*)&pbuf[0][wv][1][lane * 4] = wk;
    }
    __syncthreads();

    for (int t = 0; t < T; t += 2) {
        STEP(t);
        STEP(t + 1);
    }

    // final: finish step T-1
    {
        float4 pqQ = *(const float4*)&pqk[(T - 1) & 1][0];
        float zs = ((pqQ.x + pqQ.y) + (pqQ.z + pqQ.w)) + b2;
        float s_ = sigmoid_fast(zs);
        const int ci = T - 1;
        float cv = cbuf[((ci >> 6) & 1) * 64 + (ci & 63)];
        float df = s_ - cv;
        loss = fmaf(df, df, loss);
        if (j == 0) { out[T - 1] = s_; out[T] = loss; }
    }
}

// ---------------------------------------------------------------------------
extern "C" void kernel_launch(void* const* d_in, const int* in_sizes, int n_in,
                              void* d_out, int out_size, void* d_ws, size_t ws_size,
                              hipStream_t stream) {
    const float* phi     = (const float*)d_in[0];
    const float* C_seq   = (const float*)d_in[1];
    const float* thK     = (const float*)d_in[2];
    const float* thQ     = (const float*)d_in[3];
    const float* W10     = (const float*)d_in[4];
    const float* b10     = (const float*)d_in[5];
    const float* W20     = (const float*)d_in[6];
    const float* b20     = (const float*)d_in[7];
    const float* log_eta = (const float*)d_in[8];

    const int T    = in_sizes[1];          // 8192
    const int dphi = in_sizes[0] / T;      // 4096

    float*  uw  = (float*)d_ws;                                            // [T][128]
    float4* dd4 = (float4*)((char*)d_ws + (size_t)T * 128 * sizeof(float)); // [T]

    proj_kernel<<<T / 32, 256, 0, stream>>>(phi, thK, thQ, uw, dphi);
    dots_kernel<<<T / 4, 256, 0, stream>>>(uw, dd4, T);
    ttt_scan<<<1, 256, 0, stream>>>(uw, dd4, C_seq, W10, b10, W20, b20, log_eta,
                                    (float*)d_out, T);
}